// Round 15
// baseline (434.962 us; speedup 1.0000x reference)
//
#include <hip/hip_runtime.h>

#define NTOK 32768
#define NE   2048
#define EDIM 128
#define NQ   4

#define TOKT 64                  // tokens per block
#define CAP 16
#define MARGIN_S 0.1875f         // s-space margin (~2.9x bf16 error bound)

typedef __attribute__((ext_vector_type(8))) short short8v;   // 8 bf16
typedef __attribute__((ext_vector_type(4))) float f32x4;

__device__ __forceinline__ unsigned short bf16rne(float x) {
    unsigned u = __float_as_uint(x);
    unsigned r = 0x7FFFu + ((u >> 16) & 1u);
    return (unsigned short)((u + r) >> 16);
}

#define MFMA_BF16 __builtin_amdgcn_mfma_f32_16x16x32_bf16

// ---------------------------------------------------------------------------
// prep: per-code fp32 norms (identical serial chain to rounds 1-14) + bf16
// convert (natural layout) + zero loss accumulator.
// ---------------------------------------------------------------------------
__global__ __launch_bounds__(256) void prep_kernel(
    const float* __restrict__ cb, unsigned short* __restrict__ cb16,
    float* __restrict__ cnorm, float* __restrict__ loss_accum)
{
    const int row = blockIdx.x * 256 + threadIdx.x;   // 0..NQ*NE-1
    if (row == 0) *loss_accum = 0.0f;
    const float* src = cb + (size_t)row * EDIM;
    unsigned short* dst = cb16 + (size_t)row * EDIM;
    float s = 0.0f;
#pragma unroll
    for (int j = 0; j < EDIM / 4; ++j) {
        float4 v = ((const float4*)src)[j];
        s += v.x * v.x; s += v.y * v.y; s += v.z * v.z; s += v.w * v.w;
        ushort4 o;
        o.x = bf16rne(v.x); o.y = bf16rne(v.y);
        o.z = bf16rne(v.z); o.w = bf16rne(v.w);
        *(ushort4*)(dst + j * 4) = o;
    }
    cnorm[row] = s;
}

// ---------------------------------------------------------------------------
// One VQ level. Barrier-free 2-pass bf16-MFMA sieve, B streamed global->reg
// (L2-resident codebook). 512 thr / 8 waves: wave = code-EIGHTH (256 codes)
// x ALL 64 tokens (16 A-frags) -> grid 512 gives 16 waves/CU = 4 waves/SIMD
// (2x round-14's latency hiding; same reuse, same traffic). Exact-fp32
// refine + epilogue chains identical to rounds 9-14 (absmax 0 proven).
// ---------------------------------------------------------------------------
__global__ __launch_bounds__(512) void vq_level_kernel(
    const float* __restrict__ rin,
    const float* __restrict__ cbF,          // fp32 codebook (refine + gather)
    const unsigned short* __restrict__ cbL, // bf16 codebook (level, natural)
    const float* __restrict__ cnorm,        // [NE]
    float* __restrict__ rout,
    float* __restrict__ xq,
    float* __restrict__ idx_out,
    float* __restrict__ loss_accum,
    int level, int first)
{
    __shared__ float part[4 * TOKT];
    __shared__ float rns[TOKT];
    __shared__ float mdw[8][TOKT];
    __shared__ float smaxs[TOKT];
    __shared__ int   cnt[TOKT];
    __shared__ int   lst[TOKT * CAP];
    __shared__ float redb_d[8][TOKT];
    __shared__ int   redb_i[8][TOKT];
    __shared__ int   idx_s[TOKT];
    __shared__ float lsum[512];

    const int t    = threadIdx.x;
    const int tok0 = blockIdx.x * TOKT;
    const int w    = t >> 6;          // wave = code eighth (0..7)
    const int cl   = t & 15;          // MFMA col lane (code)
    const int lg   = (t & 63) >> 4;   // k-group
    if (t < TOKT) cnt[t] = 0;

    // ---- token norms from global rin (EXACT rounds 1-14 structure:
    //      4 groups x 32 dims, computed by threads t<256 only) ----
    if (t < 256) {
        const int tok = t & 63;
        const int dg  = t >> 6;
        float s = 0.0f;
#pragma unroll
        for (int j = 0; j < 8; ++j) {
            const int d0 = dg * 32 + j * 4;
            float4 v = *(const float4*)(rin + (size_t)(tok0 + tok) * EDIM + d0);
            s += v.x * v.x; s += v.y * v.y; s += v.z * v.z; s += v.w * v.w;
        }
        part[dg * TOKT + tok] = s;
    }
    __syncthreads();
    if (t < TOKT)
        rns[t] = ((part[t] + part[TOKT + t]) + part[2 * TOKT + t])
                 + part[3 * TOKT + t];

    // ---- A fragments: 4 row-tiles x 4 kt, straight from global rin ----
    short8v a00, a01, a02, a03, a10, a11, a12, a13;
    short8v a20, a21, a22, a23, a30, a31, a32, a33;
#define LDA(AF, RT, KT) { \
    const float* ap = rin + (size_t)(tok0 + (RT) * 16 + cl) * EDIM \
                      + (KT) * 32 + lg * 8; \
    float4 q0 = *(const float4*)ap; float4 q1 = *(const float4*)(ap + 4); \
    AF[0] = (short)bf16rne(q0.x); AF[1] = (short)bf16rne(q0.y); \
    AF[2] = (short)bf16rne(q0.z); AF[3] = (short)bf16rne(q0.w); \
    AF[4] = (short)bf16rne(q1.x); AF[5] = (short)bf16rne(q1.y); \
    AF[6] = (short)bf16rne(q1.z); AF[7] = (short)bf16rne(q1.w); }
    LDA(a00, 0, 0) LDA(a01, 0, 1) LDA(a02, 0, 2) LDA(a03, 0, 3)
    LDA(a10, 1, 0) LDA(a11, 1, 1) LDA(a12, 1, 2) LDA(a13, 1, 3)
    LDA(a20, 2, 0) LDA(a21, 2, 1) LDA(a22, 2, 2) LDA(a23, 2, 3)
    LDA(a30, 3, 0) LDA(a31, 3, 1) LDA(a32, 3, 2) LDA(a33, 3, 3)
#undef LDA

    // token bases for the 4 row-tiles (C/D row = lg*4 + reg)
    const int tb0 = lg * 4, tb1 = 16 + lg * 4, tb2 = 32 + lg * 4, tb3 = 48 + lg * 4;
    const int cbase = w * 256;        // this wave's code range (256 codes)

// one 16-code column tile: 4 global 16B loads feed 16 MFMAs (4 row-tiles)
#define CTBLK(CT, TAIL) { \
    const int code = cbase + (CT) * 16 + cl; \
    const float cn2 = -0.5f * cnorm[code]; \
    const unsigned short* bp = cbL + (size_t)code * EDIM + lg * 8; \
    short8v b0 = *(const short8v*)(bp); \
    short8v b1 = *(const short8v*)(bp + 32); \
    short8v b2 = *(const short8v*)(bp + 64); \
    short8v b3 = *(const short8v*)(bp + 96); \
    f32x4 p0 = {cn2, cn2, cn2, cn2}; f32x4 p1 = p0; \
    f32x4 p2 = p0;                   f32x4 p3 = p0; \
    p0 = MFMA_BF16(a00, b0, p0, 0, 0, 0); p1 = MFMA_BF16(a10, b0, p1, 0, 0, 0); \
    p2 = MFMA_BF16(a20, b0, p2, 0, 0, 0); p3 = MFMA_BF16(a30, b0, p3, 0, 0, 0); \
    p0 = MFMA_BF16(a01, b1, p0, 0, 0, 0); p1 = MFMA_BF16(a11, b1, p1, 0, 0, 0); \
    p2 = MFMA_BF16(a21, b1, p2, 0, 0, 0); p3 = MFMA_BF16(a31, b1, p3, 0, 0, 0); \
    p0 = MFMA_BF16(a02, b2, p0, 0, 0, 0); p1 = MFMA_BF16(a12, b2, p1, 0, 0, 0); \
    p2 = MFMA_BF16(a22, b2, p2, 0, 0, 0); p3 = MFMA_BF16(a32, b2, p3, 0, 0, 0); \
    p0 = MFMA_BF16(a03, b3, p0, 0, 0, 0); p1 = MFMA_BF16(a13, b3, p1, 0, 0, 0); \
    p2 = MFMA_BF16(a23, b3, p2, 0, 0, 0); p3 = MFMA_BF16(a33, b3, p3, 0, 0, 0); \
    TAIL }

#define T_MIN \
    md00 = fmaxf(md00, p0[0]); md01 = fmaxf(md01, p0[1]); \
    md02 = fmaxf(md02, p0[2]); md03 = fmaxf(md03, p0[3]); \
    md10 = fmaxf(md10, p1[0]); md11 = fmaxf(md11, p1[1]); \
    md12 = fmaxf(md12, p1[2]); md13 = fmaxf(md13, p1[3]); \
    md20 = fmaxf(md20, p2[0]); md21 = fmaxf(md21, p2[1]); \
    md22 = fmaxf(md22, p2[2]); md23 = fmaxf(md23, p2[3]); \
    md30 = fmaxf(md30, p3[0]); md31 = fmaxf(md31, p3[1]); \
    md32 = fmaxf(md32, p3[2]); md33 = fmaxf(md33, p3[3]);

#define PUSH1(S, TH, TOK) { if ((S) > (TH)) { \
    int pp = atomicAdd(&cnt[TOK], 1); \
    if (pp < CAP) lst[(TOK) * CAP + pp] = code; } }
#define T_PUSH \
    PUSH1(p0[0], th00, tb0 + 0) PUSH1(p0[1], th01, tb0 + 1) \
    PUSH1(p0[2], th02, tb0 + 2) PUSH1(p0[3], th03, tb0 + 3) \
    PUSH1(p1[0], th10, tb1 + 0) PUSH1(p1[1], th11, tb1 + 1) \
    PUSH1(p1[2], th12, tb1 + 2) PUSH1(p1[3], th13, tb1 + 3) \
    PUSH1(p2[0], th20, tb2 + 0) PUSH1(p2[1], th21, tb2 + 1) \
    PUSH1(p2[2], th22, tb2 + 2) PUSH1(p2[3], th23, tb2 + 3) \
    PUSH1(p3[0], th30, tb3 + 0) PUSH1(p3[1], th31, tb3 + 1) \
    PUSH1(p3[2], th32, tb3 + 2) PUSH1(p3[3], th33, tb3 + 3)

    // ---- PASS 1: per-token max of s = dot - cn/2 (no barriers) ----
    float md00 = -3.402823466e38f, md01 = md00, md02 = md00, md03 = md00;
    float md10 = md00, md11 = md00, md12 = md00, md13 = md00;
    float md20 = md00, md21 = md00, md22 = md00, md23 = md00;
    float md30 = md00, md31 = md00, md32 = md00, md33 = md00;

#pragma unroll 2
    for (int ct = 0; ct < 16; ++ct) {
        CTBLK(ct, T_MIN)
    }

    // once-per-pass reduce over the 16 code-lanes
#pragma unroll
    for (int m = 1; m < 16; m <<= 1) {
        md00 = fmaxf(md00, __shfl_xor(md00, m, 64));
        md01 = fmaxf(md01, __shfl_xor(md01, m, 64));
        md02 = fmaxf(md02, __shfl_xor(md02, m, 64));
        md03 = fmaxf(md03, __shfl_xor(md03, m, 64));
        md10 = fmaxf(md10, __shfl_xor(md10, m, 64));
        md11 = fmaxf(md11, __shfl_xor(md11, m, 64));
        md12 = fmaxf(md12, __shfl_xor(md12, m, 64));
        md13 = fmaxf(md13, __shfl_xor(md13, m, 64));
        md20 = fmaxf(md20, __shfl_xor(md20, m, 64));
        md21 = fmaxf(md21, __shfl_xor(md21, m, 64));
        md22 = fmaxf(md22, __shfl_xor(md22, m, 64));
        md23 = fmaxf(md23, __shfl_xor(md23, m, 64));
        md30 = fmaxf(md30, __shfl_xor(md30, m, 64));
        md31 = fmaxf(md31, __shfl_xor(md31, m, 64));
        md32 = fmaxf(md32, __shfl_xor(md32, m, 64));
        md33 = fmaxf(md33, __shfl_xor(md33, m, 64));
    }
    if (cl == 0) {
        mdw[w][tb0 + 0] = md00; mdw[w][tb0 + 1] = md01;
        mdw[w][tb0 + 2] = md02; mdw[w][tb0 + 3] = md03;
        mdw[w][tb1 + 0] = md10; mdw[w][tb1 + 1] = md11;
        mdw[w][tb1 + 2] = md12; mdw[w][tb1 + 3] = md13;
        mdw[w][tb2 + 0] = md20; mdw[w][tb2 + 1] = md21;
        mdw[w][tb2 + 2] = md22; mdw[w][tb2 + 3] = md23;
        mdw[w][tb3 + 0] = md30; mdw[w][tb3 + 1] = md31;
        mdw[w][tb3 + 2] = md32; mdw[w][tb3 + 3] = md33;
    }
    __syncthreads();
    if (t < TOKT) {
        float sm = mdw[0][t];
#pragma unroll
        for (int ww = 1; ww < 8; ++ww) sm = fmaxf(sm, mdw[ww][t]);
        smaxs[t] = sm;
    }
    __syncthreads();

    const float th00 = smaxs[tb0 + 0] - MARGIN_S;
    const float th01 = smaxs[tb0 + 1] - MARGIN_S;
    const float th02 = smaxs[tb0 + 2] - MARGIN_S;
    const float th03 = smaxs[tb0 + 3] - MARGIN_S;
    const float th10 = smaxs[tb1 + 0] - MARGIN_S;
    const float th11 = smaxs[tb1 + 1] - MARGIN_S;
    const float th12 = smaxs[tb1 + 2] - MARGIN_S;
    const float th13 = smaxs[tb1 + 3] - MARGIN_S;
    const float th20 = smaxs[tb2 + 0] - MARGIN_S;
    const float th21 = smaxs[tb2 + 1] - MARGIN_S;
    const float th22 = smaxs[tb2 + 2] - MARGIN_S;
    const float th23 = smaxs[tb2 + 3] - MARGIN_S;
    const float th30 = smaxs[tb3 + 0] - MARGIN_S;
    const float th31 = smaxs[tb3 + 1] - MARGIN_S;
    const float th32 = smaxs[tb3 + 2] - MARGIN_S;
    const float th33 = smaxs[tb3 + 3] - MARGIN_S;

    // ---- PASS 2: collect candidates within margin (no barriers) ----
#pragma unroll 2
    for (int ct = 0; ct < 16; ++ct) {
        CTBLK(ct, T_PUSH)
    }
    __syncthreads();

    // ---- refine: exact fp32 (rounds 1-14 chain), 8-way per token ----
    {
        const int tok = t & 63;
        const int s   = t >> 6;
        const int n   = min(cnt[tok], CAP);
        const float rn_t = rns[tok];
        const float* rrow = rin + (size_t)(tok0 + tok) * EDIM;
        float bd = 3.402823466e38f;
        int   bi = 0x7fffffff;
        for (int i = s; i < n; i += 8) {
            const int c = lst[tok * CAP + i];
            const float* cr = cbF + (size_t)c * EDIM;
            float dot = 0.0f;
#pragma unroll
            for (int j = 0; j < 32; ++j) {
                const float4 a = *(const float4*)(rrow + j * 4);
                const float4 b = *(const float4*)(cr + j * 4);
                dot = fmaf(a.x, b.x, dot); dot = fmaf(a.y, b.y, dot);
                dot = fmaf(a.z, b.z, dot); dot = fmaf(a.w, b.w, dot);
            }
            const float dd = (rn_t - 2.0f * dot) + cnorm[c];
            if (dd < bd || (dd == bd && c < bi)) { bd = dd; bi = c; }
        }
        redb_d[s][tok] = bd;
        redb_i[s][tok] = bi;
    }
    __syncthreads();
    if (t < TOKT) {
        float bd = redb_d[0][t];
        int   bi = redb_i[0][t];
#pragma unroll
        for (int s = 1; s < 8; ++s) {
            const float dd = redb_d[s][t];
            const int   ii = redb_i[s][t];
            if (dd < bd || (dd == bd && ii < bi)) { bd = dd; bi = ii; }
        }
        idx_s[t] = bi;
        idx_out[(size_t)(tok0 + t) * NQ + level] = (float)bi;
    }
    __syncthreads();

    // ---- epilogue: gather + straight-through update + loss partial ----
    {
        const int tok = t >> 3;      // 0..63
        const int dq  = t & 7;       // 8 threads per token, 16 dims each
        const int gi  = idx_s[tok];
        const float* qrow = cbF + (size_t)gi * EDIM;
        const float* rrow = rin + (size_t)(tok0 + tok) * EDIM;
        float lp = 0.0f;
#pragma unroll
        for (int k = 0; k < 4; ++k) {
            const int d0 = k * 32 + dq * 4;
            const float4 q = *(const float4*)(qrow + d0);
            const float4 r = *(const float4*)(rrow + d0);
            float4 tq, qst, rnv;
            tq.x = q.x - r.x; tq.y = q.y - r.y; tq.z = q.z - r.z; tq.w = q.w - r.w;
            qst.x = r.x + tq.x; qst.y = r.y + tq.y;
            qst.z = r.z + tq.z; qst.w = r.w + tq.w;
            rnv.x = r.x - qst.x; rnv.y = r.y - qst.y;
            rnv.z = r.z - qst.z; rnv.w = r.w - qst.w;
            const size_t go = (size_t)(tok0 + tok) * EDIM + d0;
            *(float4*)(rout + go) = rnv;
            if (first) {
                *(float4*)(xq + go) = qst;
            } else {
                float4 o = *(const float4*)(xq + go);
                o.x += qst.x; o.y += qst.y; o.z += qst.z; o.w += qst.w;
                *(float4*)(xq + go) = o;
            }
            lp += tq.x * tq.x; lp += tq.y * tq.y;
            lp += tq.z * tq.z; lp += tq.w * tq.w;
        }
        lsum[t] = lp;
    }
    __syncthreads();
#pragma unroll
    for (int s2 = 256; s2 > 0; s2 >>= 1) {
        if (t < s2) lsum[t] += lsum[t + s2];
        __syncthreads();
    }
    if (t == 0) atomicAdd(loss_accum, lsum[0]);
}

// ---------------------------------------------------------------------------
__global__ void finalize_kernel(const float* __restrict__ loss_accum,
                                float* __restrict__ out_loss)
{
    *out_loss = *loss_accum * (1.25f / (4.0f * (float)NTOK * (float)EDIM));
}

extern "C" void kernel_launch(void* const* d_in, const int* in_sizes, int n_in,
                              void* d_out, int out_size, void* d_ws, size_t ws_size,
                              hipStream_t stream)
{
    const float* x  = (const float*)d_in[0];
    const float* cb = (const float*)d_in[1];

    float* out      = (float*)d_out;
    float* xq       = out;
    float* out_loss = out + (size_t)NTOK * EDIM;
    float* idx_out  = out + (size_t)NTOK * EDIM + 1;

    float* ws             = (float*)d_ws;
    float* cnorm          = ws;                            // NQ*NE
    float* loss_accum     = ws + 8192;
    unsigned short* cb16  = (unsigned short*)(ws + 8448);  // NQ*NE*EDIM bf16
    float* r0             = ws + 8448 + (size_t)NQ * NE * EDIM / 2;

    prep_kernel<<<(NQ * NE) / 256, 256, 0, stream>>>(cb, cb16, cnorm, loss_accum);

    for (int l = 0; l < NQ; ++l) {
        const float* rin = (l == 0) ? x : r0;
        vq_level_kernel<<<NTOK / TOKT, 512, 0, stream>>>(
            rin, cb + (size_t)l * NE * EDIM,
            cb16 + (size_t)l * NE * EDIM,
            cnorm + (size_t)l * NE,
            r0, xq, idx_out, loss_accum, l, (l == 0) ? 1 : 0);
    }
    finalize_kernel<<<1, 1, 0, stream>>>(loss_accum, out_loss);
}

// Round 16
// 261.656 us; speedup vs baseline: 1.6623x; 1.6623x over previous
//
#include <hip/hip_runtime.h>

#define NTOK 32768
#define NE   2048
#define EDIM 128
#define NQ   4

#define TOKT 64                  // tokens per block
#define CHCODES 64               // codes per staged chunk (16 KB bf16)
#define NCHUNK (NE / CHCODES)    // 32
#define CAP 16
#define MARGIN 0.25f             // d-space margin (r11-proven)

typedef __attribute__((ext_vector_type(8))) short short8v;   // 8 bf16
typedef __attribute__((ext_vector_type(4))) float f32x4;

__device__ __forceinline__ unsigned short bf16rne(float x) {
    unsigned u = __float_as_uint(x);
    unsigned r = 0x7FFFu + ((u >> 16) & 1u);
    return (unsigned short)((u + r) >> 16);
}

__device__ __forceinline__ void gld16(const void* g, const void* l) {
    __builtin_amdgcn_global_load_lds(
        (const __attribute__((address_space(1))) unsigned int*)g,
        (__attribute__((address_space(3))) unsigned int*)l, 16, 0, 0);
}

#define MFMA_BF16 __builtin_amdgcn_mfma_f32_16x16x32_bf16

// ---------------------------------------------------------------------------
// prep: per-code fp32 norms (identical serial chain to rounds 1-15) + bf16
// convert with dim-XOR swizzle (dim ^ ((code&7)<<3)) + zero loss accumulator.
// ---------------------------------------------------------------------------
__global__ __launch_bounds__(256) void prep_kernel(
    const float* __restrict__ cb, unsigned short* __restrict__ cb16s,
    float* __restrict__ cnorm, float* __restrict__ loss_accum)
{
    const int row = blockIdx.x * 256 + threadIdx.x;   // 0..NQ*NE-1
    if (row == 0) *loss_accum = 0.0f;
    const float* src = cb + (size_t)row * EDIM;
    unsigned short* dst = cb16s + (size_t)row * EDIM;
    const int swz8 = (row & 7) << 3;
    float s = 0.0f;
#pragma unroll
    for (int j = 0; j < EDIM / 4; ++j) {
        float4 v = ((const float4*)src)[j];
        s += v.x * v.x; s += v.y * v.y; s += v.z * v.z; s += v.w * v.w;
        ushort4 o;
        o.x = bf16rne(v.x); o.y = bf16rne(v.y);
        o.z = bf16rne(v.z); o.w = bf16rne(v.w);
        *(ushort4*)(dst + ((j * 4) ^ swz8)) = o;
    }
    cnorm[row] = s;
}

// ---------------------------------------------------------------------------
// FUSED: all 4 VQ levels in one kernel. Block owns 64 tokens; residual lives
// in the Af LDS tile across levels (no global residual buffer, no inter-level
// launches). Per level: r11's exact 2-pass bf16-MFMA sieve (LDS-staged B,
// wave = (token-half, code-half) = 32 tok x 1024 codes) + exact-fp32 refine
// + epilogue (xq RMW to global, Af updated in place, norm partials
// recomputed with the identical 4x32-group association).
// grid = 512 blocks, 256 thr, ~76 KB LDS -> 2 blocks/CU.
// ---------------------------------------------------------------------------
__global__ __launch_bounds__(256, 2) void vq_fused_kernel(
    const float* __restrict__ x,
    const float* __restrict__ cbF0,          // fp32 codebooks [NQ][NE][EDIM]
    const unsigned short* __restrict__ cbL0, // bf16 swizzled codebooks
    const float* __restrict__ cnorm0,        // [NQ][NE]
    float* __restrict__ xq,
    float* __restrict__ idx_out,
    float* __restrict__ loss_accum)
{
    __shared__ __align__(16) float Af[TOKT][132];                  // 33792 B
    __shared__ __align__(16) unsigned short Bs[2][CHCODES * EDIM]; // 32768 B
    __shared__ float part[4 * TOKT];
    __shared__ float rns[TOKT];
    __shared__ float mdw[2][TOKT];
    __shared__ int   cnt[TOKT];
    __shared__ int   lst[TOKT * CAP];
    __shared__ float redb_d[4][TOKT];
    __shared__ int   redb_i[4][TOKT];
    __shared__ int   idx_s[TOKT];
    __shared__ float lsum[256];

    const int t     = threadIdx.x;
    const int tok0  = blockIdx.x * TOKT;
    const int w     = t >> 6;
    const int rh    = w >> 1;         // token half
    const int chalf = w & 1;          // code half within each chunk
    const int cl    = t & 15;         // MFMA col lane
    const int lg    = (t & 63) >> 4;  // k-group

    // ---- stage x -> Af (row-major) + partial norms (rounds 1-15 chain) ----
    {
        const int tok = t & 63;
        const int dg  = t >> 6;
        float s = 0.0f;
#pragma unroll
        for (int j = 0; j < 8; ++j) {
            const int d0 = dg * 32 + j * 4;
            float4 v = *(const float4*)(x + (size_t)(tok0 + tok) * EDIM + d0);
            *(float4*)&Af[tok][d0] = v;
            s += v.x * v.x; s += v.y * v.y; s += v.z * v.z; s += v.w * v.w;
        }
        part[dg * TOKT + tok] = s;
    }
    __syncthreads();

    // B read addressing (round-9-verified swizzle; code&7 == cl&7)
    const int swzk = (cl & 7) << 4;
    const int inn0 = (0   + lg * 16) ^ swzk;
    const int inn1 = (64  + lg * 16) ^ swzk;
    const int inn2 = (128 + lg * 16) ^ swzk;
    const int inn3 = (192 + lg * 16) ^ swzk;

    const int tokb0 = rh * 32 + lg * 4;      // C/D row = lg*4 + reg
    const int tokb1 = tokb0 + 16;

#define STAGE(DST, CH) { \
    const char* gs = (const char*)cbL + (size_t)(CH) * 16384 + t * 16; \
    char* ls = (char*)(DST) + (t & 192) * 16; \
    gld16(gs,         ls); \
    gld16(gs + 4096,  ls + 4096); \
    gld16(gs + 8192,  ls + 8192); \
    gld16(gs + 12288, ls + 12288); }

#define MFMAG(BUFC, CH, CT, TAIL) { \
    const char* bp = (const char*)&Bs[BUFC][0] \
                     + (chalf * 32 + (CT) * 16 + cl) * 256; \
    short8v b0 = *(const short8v*)(bp + inn0); \
    short8v b1 = *(const short8v*)(bp + inn1); \
    short8v b2 = *(const short8v*)(bp + inn2); \
    short8v b3 = *(const short8v*)(bp + inn3); \
    f32x4 ac0 = {0.f, 0.f, 0.f, 0.f}; \
    f32x4 ac1 = {0.f, 0.f, 0.f, 0.f}; \
    ac0 = MFMA_BF16(a00, b0, ac0, 0, 0, 0); \
    ac0 = MFMA_BF16(a01, b1, ac0, 0, 0, 0); \
    ac0 = MFMA_BF16(a02, b2, ac0, 0, 0, 0); \
    ac0 = MFMA_BF16(a03, b3, ac0, 0, 0, 0); \
    ac1 = MFMA_BF16(a10, b0, ac1, 0, 0, 0); \
    ac1 = MFMA_BF16(a11, b1, ac1, 0, 0, 0); \
    ac1 = MFMA_BF16(a12, b2, ac1, 0, 0, 0); \
    ac1 = MFMA_BF16(a13, b3, ac1, 0, 0, 0); \
    const int code = (CH) * CHCODES + chalf * 32 + (CT) * 16 + cl; \
    const float cn = cnorm[code]; \
    TAIL }

#define T_MIN \
    md00 = fminf(md00, (rn00 - 2.f * ac0[0]) + cn); \
    md01 = fminf(md01, (rn01 - 2.f * ac0[1]) + cn); \
    md02 = fminf(md02, (rn02 - 2.f * ac0[2]) + cn); \
    md03 = fminf(md03, (rn03 - 2.f * ac0[3]) + cn); \
    md10 = fminf(md10, (rn10 - 2.f * ac1[0]) + cn); \
    md11 = fminf(md11, (rn11 - 2.f * ac1[1]) + cn); \
    md12 = fminf(md12, (rn12 - 2.f * ac1[2]) + cn); \
    md13 = fminf(md13, (rn13 - 2.f * ac1[3]) + cn);

#define PUSH(AC, R, RN, TH, TOKB) { \
    float dd = ((RN) - 2.f * AC[R]) + cn; \
    if (dd < (TH)) { int p = atomicAdd(&cnt[(TOKB) + R], 1); \
                     if (p < CAP) lst[((TOKB) + R) * CAP + p] = code; } }
#define T_CAND \
    PUSH(ac0, 0, rn00, th00, tokb0) PUSH(ac0, 1, rn01, th01, tokb0) \
    PUSH(ac0, 2, rn02, th02, tokb0) PUSH(ac0, 3, rn03, th03, tokb0) \
    PUSH(ac1, 0, rn10, th10, tokb1) PUSH(ac1, 1, rn11, th11, tokb1) \
    PUSH(ac1, 2, rn12, th12, tokb1) PUSH(ac1, 3, rn13, th13, tokb1)

#define CH_P1(B, CH) { MFMAG(B, CH, 0, T_MIN)  MFMAG(B, CH, 1, T_MIN)  }
#define CH_P2(B, CH) { MFMAG(B, CH, 0, T_CAND) MFMAG(B, CH, 1, T_CAND) }

#pragma unroll 1
    for (int l = 0; l < NQ; ++l) {
        const float* cbF          = cbF0 + (size_t)l * NE * EDIM;
        const unsigned short* cbL = cbL0 + (size_t)l * NE * EDIM;
        const float* cnorm        = cnorm0 + (size_t)l * NE;

        // token norms (same association as rounds 1-15) + cnt reset
        if (t < TOKT) {
            rns[t] = ((part[t] + part[TOKT + t]) + part[2 * TOKT + t])
                     + part[3 * TOKT + t];
            cnt[t] = 0;
        }

        // ---- A fragments: 2 row-tiles x 4 kt from Af (LDS) ----
        short8v a00, a01, a02, a03, a10, a11, a12, a13;
#define LDA(AF, AROW, KT) { \
    float4 p0 = *(const float4*)&Af[AROW][(KT) * 32 + lg * 8]; \
    float4 p1 = *(const float4*)&Af[AROW][(KT) * 32 + lg * 8 + 4]; \
    AF[0] = (short)bf16rne(p0.x); AF[1] = (short)bf16rne(p0.y); \
    AF[2] = (short)bf16rne(p0.z); AF[3] = (short)bf16rne(p0.w); \
    AF[4] = (short)bf16rne(p1.x); AF[5] = (short)bf16rne(p1.y); \
    AF[6] = (short)bf16rne(p1.z); AF[7] = (short)bf16rne(p1.w); }
        {
            const int ar0 = rh * 32 + cl, ar1 = rh * 32 + 16 + cl;
            LDA(a00, ar0, 0) LDA(a01, ar0, 1) LDA(a02, ar0, 2) LDA(a03, ar0, 3)
            LDA(a10, ar1, 0) LDA(a11, ar1, 1) LDA(a12, ar1, 2) LDA(a13, ar1, 3)
        }
#undef LDA

        // ---- PASS 1: per-token min of approx distance ----
        STAGE(&Bs[0][0], 0)
        __syncthreads();                 // chunk0 resident; rns visible

        const float rn00 = rns[tokb0 + 0], rn01 = rns[tokb0 + 1];
        const float rn02 = rns[tokb0 + 2], rn03 = rns[tokb0 + 3];
        const float rn10 = rns[tokb1 + 0], rn11 = rns[tokb1 + 1];
        const float rn12 = rns[tokb1 + 2], rn13 = rns[tokb1 + 3];

        float md00 = 3.402823466e38f, md01 = md00, md02 = md00, md03 = md00;
        float md10 = md00, md11 = md00, md12 = md00, md13 = md00;

        for (int c2 = 0; c2 < NCHUNK / 2; ++c2) {
            const int c = c2 * 2;
            STAGE(&Bs[1][0], c + 1)
            CH_P1(0, c)
            __syncthreads();
            if (c + 2 < NCHUNK) STAGE(&Bs[0][0], c + 2)
            CH_P1(1, c + 1)
            __syncthreads();
        }

        // reduce min across the 16 code-lanes (cl), then across wave pair
#pragma unroll
        for (int m = 1; m < 16; m <<= 1) {
            md00 = fminf(md00, __shfl_xor(md00, m, 64));
            md01 = fminf(md01, __shfl_xor(md01, m, 64));
            md02 = fminf(md02, __shfl_xor(md02, m, 64));
            md03 = fminf(md03, __shfl_xor(md03, m, 64));
            md10 = fminf(md10, __shfl_xor(md10, m, 64));
            md11 = fminf(md11, __shfl_xor(md11, m, 64));
            md12 = fminf(md12, __shfl_xor(md12, m, 64));
            md13 = fminf(md13, __shfl_xor(md13, m, 64));
        }
        if (cl == 0) {
            mdw[chalf][tokb0 + 0] = md00; mdw[chalf][tokb0 + 1] = md01;
            mdw[chalf][tokb0 + 2] = md02; mdw[chalf][tokb0 + 3] = md03;
            mdw[chalf][tokb1 + 0] = md10; mdw[chalf][tokb1 + 1] = md11;
            mdw[chalf][tokb1 + 2] = md12; mdw[chalf][tokb1 + 3] = md13;
        }

        // ---- PASS 2 prologue: stage chunk0 while combining mins ----
        STAGE(&Bs[0][0], 0)
        __syncthreads();                 // mdw visible + chunk0 resident

        const float th00 = fminf(mdw[0][tokb0 + 0], mdw[1][tokb0 + 0]) + MARGIN;
        const float th01 = fminf(mdw[0][tokb0 + 1], mdw[1][tokb0 + 1]) + MARGIN;
        const float th02 = fminf(mdw[0][tokb0 + 2], mdw[1][tokb0 + 2]) + MARGIN;
        const float th03 = fminf(mdw[0][tokb0 + 3], mdw[1][tokb0 + 3]) + MARGIN;
        const float th10 = fminf(mdw[0][tokb1 + 0], mdw[1][tokb1 + 0]) + MARGIN;
        const float th11 = fminf(mdw[0][tokb1 + 1], mdw[1][tokb1 + 1]) + MARGIN;
        const float th12 = fminf(mdw[0][tokb1 + 2], mdw[1][tokb1 + 2]) + MARGIN;
        const float th13 = fminf(mdw[0][tokb1 + 3], mdw[1][tokb1 + 3]) + MARGIN;

        for (int c2 = 0; c2 < NCHUNK / 2; ++c2) {
            const int c = c2 * 2;
            STAGE(&Bs[1][0], c + 1)
            CH_P2(0, c)
            __syncthreads();
            if (c + 2 < NCHUNK) STAGE(&Bs[0][0], c + 2)
            CH_P2(1, c + 1)
            __syncthreads();
        }

        // ---- refine: exact fp32 (rounds 1-15 chain), 4-way per token ----
        {
            const int tok = t & 63;
            const int s   = t >> 6;
            const int n   = min(cnt[tok], CAP);
            const float rn_t = rns[tok];
            float bd = 3.402823466e38f;
            int   bi = 0x7fffffff;
            for (int i = s; i < n; i += 4) {
                const int c = lst[tok * CAP + i];
                const float* cr = cbF + (size_t)c * EDIM;
                float dot = 0.0f;
#pragma unroll 8
                for (int d = 0; d < EDIM; ++d)
                    dot = fmaf(Af[tok][d], cr[d], dot);
                const float dd = (rn_t - 2.0f * dot) + cnorm[c];
                if (dd < bd || (dd == bd && c < bi)) { bd = dd; bi = c; }
            }
            redb_d[s][tok] = bd;
            redb_i[s][tok] = bi;
        }
        __syncthreads();
        if (t < TOKT) {
            float bd = redb_d[0][t];
            int   bi = redb_i[0][t];
#pragma unroll
            for (int s = 1; s < 4; ++s) {
                const float dd = redb_d[s][t];
                const int   ii = redb_i[s][t];
                if (dd < bd || (dd == bd && ii < bi)) { bd = dd; bi = ii; }
            }
            idx_s[t] = bi;
            idx_out[(size_t)(tok0 + t) * NQ + l] = (float)bi;
        }
        __syncthreads();

        // ---- epilogue: gather + straight-through; Af <- r_next in place ----
        {
            const int tok = t >> 2;
            const int dq  = t & 3;
            const int gi  = idx_s[tok];
            const float* qrow = cbF + (size_t)gi * EDIM;
            float lp = 0.0f;
#pragma unroll
            for (int k = 0; k < 8; ++k) {
                const int d0 = k * 16 + dq * 4;
                const float4 q = *(const float4*)(qrow + d0);
                const float4 r = *(const float4*)&Af[tok][d0];
                float4 tq, qst, rnv;
                tq.x = q.x - r.x; tq.y = q.y - r.y;
                tq.z = q.z - r.z; tq.w = q.w - r.w;
                qst.x = r.x + tq.x; qst.y = r.y + tq.y;
                qst.z = r.z + tq.z; qst.w = r.w + tq.w;
                rnv.x = r.x - qst.x; rnv.y = r.y - qst.y;
                rnv.z = r.z - qst.z; rnv.w = r.w - qst.w;
                *(float4*)&Af[tok][d0] = rnv;                  // residual update
                const size_t go = (size_t)(tok0 + tok) * EDIM + d0;
                if (l == 0) {
                    *(float4*)(xq + go) = qst;
                } else {
                    float4 o = *(const float4*)(xq + go);
                    o.x += qst.x; o.y += qst.y; o.z += qst.z; o.w += qst.w;
                    *(float4*)(xq + go) = o;
                }
                lp += tq.x * tq.x; lp += tq.y * tq.y;
                lp += tq.z * tq.z; lp += tq.w * tq.w;
            }
            lsum[t] = lp;
        }
        __syncthreads();
#pragma unroll
        for (int s2 = 128; s2 > 0; s2 >>= 1) {
            if (t < s2) lsum[t] += lsum[t + s2];
            __syncthreads();
        }
        if (t == 0) atomicAdd(loss_accum, lsum[0]);

        // ---- recompute norm partials from updated Af (same association) ----
        if (l + 1 < NQ) {
            const int tok = t & 63;
            const int dg  = t >> 6;
            float s = 0.0f;
#pragma unroll
            for (int j = 0; j < 8; ++j) {
                const int d0 = dg * 32 + j * 4;
                const float4 v = *(const float4*)&Af[tok][d0];
                s += v.x * v.x; s += v.y * v.y;
                s += v.z * v.z; s += v.w * v.w;
            }
            part[dg * TOKT + tok] = s;
        }
        __syncthreads();
    }
}

// ---------------------------------------------------------------------------
__global__ void finalize_kernel(const float* __restrict__ loss_accum,
                                float* __restrict__ out_loss)
{
    *out_loss = *loss_accum * (1.25f / (4.0f * (float)NTOK * (float)EDIM));
}

extern "C" void kernel_launch(void* const* d_in, const int* in_sizes, int n_in,
                              void* d_out, int out_size, void* d_ws, size_t ws_size,
                              hipStream_t stream)
{
    const float* x  = (const float*)d_in[0];
    const float* cb = (const float*)d_in[1];

    float* out      = (float*)d_out;
    float* xq       = out;
    float* out_loss = out + (size_t)NTOK * EDIM;
    float* idx_out  = out + (size_t)NTOK * EDIM + 1;

    float* ws             = (float*)d_ws;
    float* cnorm          = ws;                            // NQ*NE
    float* loss_accum     = ws + 8192;
    unsigned short* cb16s = (unsigned short*)(ws + 8448);  // NQ*NE*EDIM bf16

    prep_kernel<<<(NQ * NE) / 256, 256, 0, stream>>>(cb, cb16s, cnorm, loss_accum);

    vq_fused_kernel<<<NTOK / TOKT, 256, 0, stream>>>(
        x, cb, cb16s, cnorm, xq, idx_out, loss_accum);

    finalize_kernel<<<1, 1, 0, stream>>>(loss_accum, out_loss);
}